// Round 11
// baseline (85.415 us; speedup 1.0000x reference)
//
#include <hip/hip_runtime.h>
#include <cstdint>

typedef __bf16 v8bf __attribute__((ext_vector_type(8)));
typedef float f32x4 __attribute__((ext_vector_type(4)));
typedef int i32x4 __attribute__((ext_vector_type(4)));
typedef uint16_t u16;
typedef uint32_t u32;
typedef u16 ushort8 __attribute__((ext_vector_type(8)));

__device__ __forceinline__ u16 f2bf(float f) {
  u32 u = __float_as_uint(f);
  u += 0x7FFFu + ((u >> 16) & 1u);   // round-to-nearest-even
  return (u16)(u >> 16);
}
__device__ __forceinline__ float bf2f(u16 h) {
  return __uint_as_float((u32)h << 16);
}

#define AS1(p) ((__attribute__((address_space(1))) void*)(p))

__device__ __forceinline__ v8bf ds_read_b128f(u32 addr) {
  i32x4 r;
  asm volatile("ds_read_b128 %0, %1" : "=v"(r) : "v"(addr));
  return __builtin_bit_cast(v8bf, r);
}

// Counted waits: NO clobbers; order pinned with sched_barrier(0) (rule #18).
#define WAITV(N)                                         \
  do {                                                   \
    __builtin_amdgcn_sched_barrier(0);                   \
    asm volatile("s_waitcnt vmcnt(" #N ")");             \
    __builtin_amdgcn_sched_barrier(0);                   \
  } while (0)
#define WAITL(N)                                         \
  do {                                                   \
    __builtin_amdgcn_sched_barrier(0);                   \
    asm volatile("s_waitcnt lgkmcnt(" #N ")");           \
    __builtin_amdgcn_sched_barrier(0);                   \
  } while (0)

// ---------------- K1: 1/||x_row|| ----------------
__global__ __launch_bounds__(256) void k_rownorm(const float* __restrict__ x,
                                                 float* __restrict__ rnorm) {
  const int row = blockIdx.x;
  const float4 v = ((const float4*)(x + (size_t)row * 1024))[threadIdx.x];
  float s = v.x * v.x + v.y * v.y + v.z * v.z + v.w * v.w;
#pragma unroll
  for (int off = 32; off > 0; off >>= 1) s += __shfl_down(s, off, 64);
  __shared__ float ps[4];
  if ((threadIdx.x & 63) == 0) ps[threadIdx.x >> 6] = s;
  __syncthreads();
  if (threadIdx.x == 0) {
    float t = ps[0] + ps[1] + ps[2] + ps[3];
    rnorm[row] = 1.0f / sqrtf(t);  // norms ~32, eps clamp never binds
  }
}

// ---------------- K2: build Y = bf16(x*rn) [8192][1024], Wt = bf16(x*sqrt(rn))^T [1024][8192] ----------------
__global__ __launch_bounds__(256) void k_build(const float* __restrict__ x,
                                               const float* __restrict__ rnorm,
                                               u16* __restrict__ Y,
                                               u16* __restrict__ Wt) {
  __shared__ float tile[64][65];
  __shared__ float rn[64], sq[64];
  const int d0 = blockIdx.x * 64;   // 0..1023
  const int i0 = blockIdx.y * 64;   // 0..8191
  const int tr = threadIdx.x >> 6;  // 0..3
  const int tc = threadIdx.x & 63;
#pragma unroll
  for (int it = 0; it < 16; ++it) {
    int r = it * 4 + tr;
    tile[r][tc] = x[(size_t)(i0 + r) * 1024 + d0 + tc];
  }
  if (threadIdx.x < 64) {
    float rv = rnorm[i0 + threadIdx.x];
    rn[threadIdx.x] = rv;
    sq[threadIdx.x] = sqrtf(rv);
  }
  __syncthreads();
#pragma unroll
  for (int it = 0; it < 16; ++it) {
    int r = it * 4 + tr;
    Y[(size_t)(i0 + r) * 1024 + d0 + tc] = f2bf(tile[r][tc] * rn[r]);
  }
#pragma unroll
  for (int it = 0; it < 16; ++it) {
    int rr = it * 4 + tr;            // d within tile
    Wt[(size_t)(d0 + rr) * 8192 + i0 + tc] = f2bf(tile[tc][rr] * sq[tc]);
  }
}

// ---------------- GEMM1 (SYRK): Z-partials = Wt * Wt^T, m201-exact geometry ----------------
// BM=BN=256, BK=32, 8 waves (2M x 4N), per-wave OUT = 128x64 (acc 128 f32/lane).
// LDS ring-4 x 32KB (A [256][64B] @0, B @16384) = 128KB. Per K-tile 2 phases:
//   P1: {8 ds_read (A-half0 + B) || 2 stage(A of T+3) -> barrier -> lgkm(0)
//        -> setprio -> 16 MFMA (C top-half) -> barrier}
//   P2: {4 ds_read (A-half1, B reused in regs) || 2 stage(B of T+3) -> barrier
//        -> lgkm(0) -> 16 MFMA (C bottom) -> vmcnt(8) -> barrier}
// 64B-row swizzle (conflict-free by construction): slot ^= (r&3)^((r>>2)&3);
// inverse applied on per-lane global source (DMA dest linear) — rule #21.
// Grid 256 = 16 tiles (4x4 of 256^2) x split-K 16 (2 slices/XCD, L2-resident).
__global__ __launch_bounds__(512, 1) void k_syrk(const u16* __restrict__ W,
                                                 u16* __restrict__ part) {
  __shared__ char lds[4 * 32768] __attribute__((aligned(128)));
  const int tid = threadIdx.x;
  const int wave = tid >> 6;       // 0..7
  const int lane = tid & 63;
  const int wm = wave >> 2;        // 0..1  (128-row band)
  const int wn = wave & 3;         // 0..3  (64-col band)

  const int xcd = blockIdx.x & 7;
  const int local = blockIdx.x >> 3;        // 0..31
  const int zi = xcd * 2 + (local >> 4);    // 0..15 K-slice
  const int tile = local & 15;              // 0..15
  const int m0 = (tile >> 2) * 256;
  const int n0 = (tile & 3) * 256;
  const int k_start = zi * 512;
  const int nt = 16;                        // 512 / BK32

  f32x4 acc[8][4] = {};

  const int frow = lane & 15;
  // read-side swizzled 16B slot (constant per lane for all frags)
  const u32 swr = (u32)((((lane >> 4) ^ (frow & 3) ^ ((frow >> 2) & 3)) & 3) << 4);

  // staging: round j covers rows j*128 + wave*16 + (lane>>2); chunk inverse-swizzled
  const int srow = (wave << 4) + (lane >> 2);
  const int chunk = (lane & 3) ^ ((lane >> 2) & 3) ^ ((lane >> 4) & 3);
  const u16* gA = W + (size_t)(m0 + srow) * 8192 + k_start + chunk * 8;
  const u16* gB = W + (size_t)(n0 + srow) * 8192 + k_start + chunk * 8;

  typedef __attribute__((address_space(3))) char* ldsp;
  ldsp l3 = (ldsp)((__attribute__((address_space(3))) void*)&lds[0]);
  const u32 lds0 = (u32)(uintptr_t)l3;

#define GLA(buf, kt, j)                                                        \
  __builtin_amdgcn_global_load_lds(                                            \
      AS1(gA + (size_t)(kt) * 32 + (size_t)(j) * 128 * 8192),                  \
      (l3 + (buf) * 32768 + (j) * 8192 + wave * 1024), 16, 0, 0)
#define GLB(buf, kt, j)                                                        \
  __builtin_amdgcn_global_load_lds(                                            \
      AS1(gB + (size_t)(kt) * 32 + (size_t)(j) * 128 * 8192),                  \
      (l3 + (buf) * 32768 + 16384 + (j) * 8192 + wave * 1024), 16, 0, 0)

  // prologue: tiles 0,1,2 in flight (12 loads); T0 resident after vmcnt(8)
  GLA(0, 0, 0); GLA(0, 0, 1); GLB(0, 0, 0); GLB(0, 0, 1);
  GLA(1, 1, 0); GLA(1, 1, 1); GLB(1, 1, 0); GLB(1, 1, 1);
  GLA(2, 2, 0); GLA(2, 2, 1); GLB(2, 2, 0); GLB(2, 2, 1);
  WAITV(8);
  __builtin_amdgcn_s_barrier();

  for (int t = 0; t < nt; ++t) {
    const int bufc = t & 3;
    const int bufs = (t + 3) & 3;
    const bool pf = (t + 3 < nt);
    const u32 bb = lds0 + (u32)bufc * 32768;
    const u32 aA = bb + (u32)((wm * 128 + frow) * 64) + swr;
    const u32 aB = bb + 16384u + (u32)((wn * 64 + frow) * 64) + swr;
    v8bf a[4], b[4];
    // ---- P1: C top-half (rows wm*128 + 0..63) ----
#pragma unroll
    for (int nj = 0; nj < 4; ++nj) b[nj] = ds_read_b128f(aB + nj * 1024);
#pragma unroll
    for (int mi = 0; mi < 4; ++mi) a[mi] = ds_read_b128f(aA + mi * 1024);
    if (pf) { GLA(bufs, t + 3, 0); GLA(bufs, t + 3, 1); }
    __builtin_amdgcn_s_barrier();
    WAITL(0);
    __builtin_amdgcn_s_setprio(1);
#pragma unroll
    for (int mi = 0; mi < 4; ++mi)
#pragma unroll
      for (int nj = 0; nj < 4; ++nj)
        acc[mi][nj] = __builtin_amdgcn_mfma_f32_16x16x32_bf16(a[mi], b[nj], acc[mi][nj], 0, 0, 0);
    __builtin_amdgcn_s_setprio(0);
    __builtin_amdgcn_s_barrier();
    // ---- P2: C bottom-half (rows wm*128 + 64..127), B reused in regs ----
    v8bf a2[4];
#pragma unroll
    for (int mi = 0; mi < 4; ++mi) a2[mi] = ds_read_b128f(aA + 4096 + mi * 1024);
    if (pf) { GLB(bufs, t + 3, 0); GLB(bufs, t + 3, 1); }
    __builtin_amdgcn_s_barrier();
    WAITL(0);
    __builtin_amdgcn_s_setprio(1);
#pragma unroll
    for (int mi = 0; mi < 4; ++mi)
#pragma unroll
      for (int nj = 0; nj < 4; ++nj)
        acc[4 + mi][nj] = __builtin_amdgcn_mfma_f32_16x16x32_bf16(a2[mi], b[nj], acc[4 + mi][nj], 0, 0, 0);
    __builtin_amdgcn_s_setprio(0);
    if (t + 3 < nt) { WAITV(8); }        // T+1 resident for next iter
    else if (t + 2 < nt) { WAITV(4); }
    else if (t + 1 < nt) { WAITV(0); }
    __builtin_amdgcn_s_barrier();
  }
#undef GLA
#undef GLB

  // C/D layout (verified): col = lane&15, row = (lane>>4)*4 + reg
  const int crow = (lane >> 4) * 4;
  const int ccol = lane & 15;
  const size_t tb = ((size_t)(zi * 16 + tile)) << 16;   // 256x256 tile base
#pragma unroll
  for (int mi = 0; mi < 8; ++mi) {
#pragma unroll
    for (int nj = 0; nj < 4; ++nj) {
      const int rl = wm * 128 + mi * 16 + crow;   // 0..255
      const int cl = wn * 64 + nj * 16 + ccol;    // 0..255
#pragma unroll
      for (int r = 0; r < 4; ++r)
        part[tb + (size_t)(rl + r) * 256 + cl] = f2bf(acc[mi][nj][r]);
    }
  }
}

// ---------------- K4: reduce 16 bf16 split-K partials -> bf16 Z (diag -> zdiag f32) ----------------
// partials layout: part[zi][tile=(m>>8)*4+(n>>8)][256][256]
__global__ __launch_bounds__(256) void k_reduce1(const u16* __restrict__ part,
                                                 u16* __restrict__ Ztb,
                                                 float* __restrict__ zdiag) {
  const int v = blockIdx.x * 256 + threadIdx.x;  // 0..131071
  const int base = v * 8;                        // over 1024*1024, 8 at a time
  const int m = base >> 10, nn = base & 1023;
  const size_t po = (((size_t)((m >> 8) * 4 + (nn >> 8))) << 16) +
                    (size_t)(m & 255) * 256 + (nn & 255);
  float s[8] = {0, 0, 0, 0, 0, 0, 0, 0};
#pragma unroll
  for (int p = 0; p < 16; ++p) {
    ushort8 pk = *(const ushort8*)(part + (((size_t)p) << 20) + po);
#pragma unroll
    for (int j = 0; j < 8; ++j) s[j] += bf2f(pk[j]);
  }
  ushort8 o;
#pragma unroll
  for (int j = 0; j < 8; ++j) {
    if (m == nn + j) { zdiag[m] = s[j]; o[j] = 0; }
    else o[j] = f2bf(s[j]);
  }
  *(ushort8*)(Ztb + (size_t)m * 1024 + nn) = o;
}

// ---------------- GEMM2: out = sigmoid(Y*Ztb^T + x*rn*zdiag) — R10-exact (control arm) ----------------
__global__ __launch_bounds__(512, 1) void k_gemm2(
    const u16* __restrict__ A, const u16* __restrict__ B, float* __restrict__ C,
    const float* __restrict__ Xf, const float* __restrict__ rnorm,
    const float* __restrict__ zdiag) {
  __shared__ char lds[3 * 49152] __attribute__((aligned(128)));
  const int tid = threadIdx.x;
  const int wave = tid >> 6;
  const int lane = tid & 63;
  const int wm = wave >> 1;
  const int wn = wave & 1;
  const int b = blockIdx.x;
  const int m0 = ((b & 7) * 4 + ((b >> 3) & 3)) * 256;  // 4 m-panels per XCD
  const int n0 = (b >> 5) * 128;
  const int K = 1024;
  const int nt = 16;

  f32x4 acc[4][4] = {};
  const int frow = lane & 15;
  const u32 sw0 = (u32)(((lane >> 4) ^ (frow & 7)) << 4);
  const int srA = lane >> 3;
  const int swz8 = ((lane & 7) ^ srA) << 3;
  const u16* gA_l = A + (size_t)(m0 + wave * 32 + srA) * K + swz8;
  const u16* gB_l = B + (size_t)(n0 + wave * 16 + srA) * K + swz8;

  typedef __attribute__((address_space(3))) char* ldsp;
  ldsp l3 = (ldsp)((__attribute__((address_space(3))) void*)&lds[0]);
  const u32 lds0 = (u32)(uintptr_t)l3;

#define GLOAD_A(buf, kt, j)                                                    \
  __builtin_amdgcn_global_load_lds(                                            \
      AS1(gA_l + (size_t)(kt) * 64 + (size_t)(j) * 8 * K),                     \
      (l3 + (size_t)(buf) * 49152 + wave * 4096 + (j) * 1024), 16, 0, 0)
#define GLOAD_B(buf, kt, j)                                                    \
  __builtin_amdgcn_global_load_lds(                                            \
      AS1(gB_l + (size_t)(kt) * 64 + (size_t)(j) * 8 * K),                     \
      (l3 + (size_t)(buf) * 49152 + 32768 + wave * 2048 + (j) * 1024), 16, 0, 0)
#define STAGE6(buf, kt)                                                        \
  do {                                                                         \
    GLOAD_A(buf, kt, 0); GLOAD_A(buf, kt, 1);                                  \
    GLOAD_A(buf, kt, 2); GLOAD_A(buf, kt, 3);                                  \
    GLOAD_B(buf, kt, 0); GLOAD_B(buf, kt, 1);                                  \
  } while (0)
#define MFMA16()                                                               \
  do {                                                                         \
    __builtin_amdgcn_s_setprio(1);                                             \
    _Pragma("unroll")                                                          \
    for (int mi = 0; mi < 4; ++mi)                                             \
      _Pragma("unroll")                                                        \
      for (int ni = 0; ni < 4; ++ni)                                           \
        acc[mi][ni] = __builtin_amdgcn_mfma_f32_16x16x32_bf16(af[mi], bf[ni], acc[mi][ni], 0, 0, 0); \
    __builtin_amdgcn_s_setprio(0);                                             \
  } while (0)

  STAGE6(0, 0);
  STAGE6(1, 1);
  WAITV(6);
  __builtin_amdgcn_s_barrier();
  int cbuf = 0, nbuf = 2;
  for (int t = 0; t < nt; ++t) {
    const u32 bb = lds0 + (u32)cbuf * 49152;
    const u32 aA = bb + (u32)((wm * 64 + frow) * 128) + sw0;
    const u32 aB = bb + 32768u + (u32)((wn * 64 + frow) * 128) + sw0;
    const bool pf = (t + 2 < nt);
    {
      v8bf af[4], bf[4];
#pragma unroll
      for (int i = 0; i < 4; ++i) af[i] = ds_read_b128f(aA + i * 2048);
#pragma unroll
      for (int i = 0; i < 4; ++i) bf[i] = ds_read_b128f(aB + i * 2048);
      if (pf) { GLOAD_A(nbuf, t + 2, 0); GLOAD_A(nbuf, t + 2, 1); GLOAD_A(nbuf, t + 2, 2); }
      __builtin_amdgcn_s_barrier();
      WAITL(0);
      MFMA16();
      __builtin_amdgcn_s_barrier();
    }
    {
      v8bf af[4], bf[4];
#pragma unroll
      for (int i = 0; i < 4; ++i) af[i] = ds_read_b128f((aA + i * 2048) ^ 0x40);
#pragma unroll
      for (int i = 0; i < 4; ++i) bf[i] = ds_read_b128f((aB + i * 2048) ^ 0x40);
      if (pf) { GLOAD_A(nbuf, t + 2, 3); GLOAD_B(nbuf, t + 2, 0); GLOAD_B(nbuf, t + 2, 1); }
      __builtin_amdgcn_s_barrier();
      WAITL(0);
      MFMA16();
      if (t + 2 < nt) { WAITV(6); }
      else if (t + 1 < nt) { WAITV(0); }
      __builtin_amdgcn_s_barrier();
    }
    cbuf = (cbuf + 1 == 3) ? 0 : cbuf + 1;
    nbuf = (nbuf + 1 == 3) ? 0 : nbuf + 1;
  }
#undef STAGE6
#undef GLOAD_A
#undef GLOAD_B
#undef MFMA16

  const int crow = (lane >> 4) * 4;
  const int ccol = lane & 15;
#pragma unroll
  for (int mi = 0; mi < 4; ++mi) {
#pragma unroll
    for (int ni = 0; ni < 4; ++ni) {
      const int rl = wm * 64 + mi * 16 + crow;
      const int cl = wn * 64 + ni * 16 + ccol;
#pragma unroll
      for (int r = 0; r < 4; ++r) {
        const int row = m0 + rl + r;
        const int col = n0 + cl;
        const size_t o = (size_t)row * 1024 + col;
        float z = acc[mi][ni][r] + Xf[o] * rnorm[row] * zdiag[col];
        C[o] = 1.0f / (1.0f + __expf(-z));
      }
    }
  }
}

extern "C" void kernel_launch(void* const* d_in, const int* in_sizes, int n_in,
                              void* d_out, int out_size, void* d_ws, size_t ws_size,
                              hipStream_t stream) {
  const float* x = (const float*)d_in[0];
  float* out = (float*)d_out;
  char* ws = (char*)d_ws;

  // ws layout (~34.1 MB): rnorm | Y | Wt | Ztb | zdiag
  float* rnorm = (float*)ws;                                   // 32 KB
  u16* Y    = (u16*)(ws + (1u << 16));                         // 16 MB
  u16* Wt   = (u16*)(ws + (1u << 16) + (16u << 20));           // 16 MB
  u16* Ztb  = (u16*)(ws + (1u << 16) + (32u << 20));           // 2 MB
  float* zdiag = (float*)(ws + (1u << 16) + (34u << 20));      // 4 KB
  u16* part = (u16*)d_out;  // 16 x 2 MB bf16 split-K partials (32 MB = d_out)

  k_rownorm<<<8192, 256, 0, stream>>>(x, rnorm);
  k_build<<<dim3(16, 128), 256, 0, stream>>>(x, rnorm, Y, Wt);
  // Z[d][e] = sum_i Wt[d][i]*Wt[e][i]: 16 tiles (256x256) x 16 K-slices = 256 blocks
  k_syrk<<<256, 512, 0, stream>>>(Wt, part);
  k_reduce1<<<512, 256, 0, stream>>>(part, Ztb, zdiag);
  // out[i][d] = sigmoid( sum_k Y[i][k]*Ztb[d][k] + x[i][d]*rn[i]*zdiag[d] ): 256 blocks
  k_gemm2<<<256, 512, 0, stream>>>(Y, Ztb, out, x, rnorm, zdiag);
}

// Round 12
// 70.743 us; speedup vs baseline: 1.2074x; 1.2074x over previous
//
#include <hip/hip_runtime.h>
#include <cstdint>

typedef __bf16 v8bf __attribute__((ext_vector_type(8)));
typedef float f32x4 __attribute__((ext_vector_type(4)));
typedef int i32x4 __attribute__((ext_vector_type(4)));
typedef uint16_t u16;
typedef uint32_t u32;
typedef u16 ushort8 __attribute__((ext_vector_type(8)));

__device__ __forceinline__ u16 f2bf(float f) {
  u32 u = __float_as_uint(f);
  u += 0x7FFFu + ((u >> 16) & 1u);   // round-to-nearest-even
  return (u16)(u >> 16);
}
__device__ __forceinline__ float bf2f(u16 h) {
  return __uint_as_float((u32)h << 16);
}

#define AS1(p) ((__attribute__((address_space(1))) void*)(p))

__device__ __forceinline__ v8bf ds_read_b128f(u32 addr) {
  i32x4 r;
  asm volatile("ds_read_b128 %0, %1" : "=v"(r) : "v"(addr));
  return __builtin_bit_cast(v8bf, r);
}

// Counted waits: NO clobbers; order pinned with sched_barrier(0) (rule #18).
#define WAITV(N)                                         \
  do {                                                   \
    __builtin_amdgcn_sched_barrier(0);                   \
    asm volatile("s_waitcnt vmcnt(" #N ")");             \
    __builtin_amdgcn_sched_barrier(0);                   \
  } while (0)
#define WAITL(N)                                         \
  do {                                                   \
    __builtin_amdgcn_sched_barrier(0);                   \
    asm volatile("s_waitcnt lgkmcnt(" #N ")");           \
    __builtin_amdgcn_sched_barrier(0);                   \
  } while (0)

// ---------------- K1: 1/||x_row|| ----------------
__global__ __launch_bounds__(256) void k_rownorm(const float* __restrict__ x,
                                                 float* __restrict__ rnorm) {
  const int row = blockIdx.x;
  const float4 v = ((const float4*)(x + (size_t)row * 1024))[threadIdx.x];
  float s = v.x * v.x + v.y * v.y + v.z * v.z + v.w * v.w;
#pragma unroll
  for (int off = 32; off > 0; off >>= 1) s += __shfl_down(s, off, 64);
  __shared__ float ps[4];
  if ((threadIdx.x & 63) == 0) ps[threadIdx.x >> 6] = s;
  __syncthreads();
  if (threadIdx.x == 0) {
    float t = ps[0] + ps[1] + ps[2] + ps[3];
    rnorm[row] = 1.0f / sqrtf(t);  // norms ~32, eps clamp never binds
  }
}

// ---------------- K2: build Y = bf16(x*rn) [8192][1024], Wt = bf16(x*sqrt(rn))^T [1024][8192] ----------------
// Z = W^T W (SYRK form): Z[d][e] = sum_i x_id*x_ie*rn_i.
__global__ __launch_bounds__(256) void k_build(const float* __restrict__ x,
                                               const float* __restrict__ rnorm,
                                               u16* __restrict__ Y,
                                               u16* __restrict__ Wt) {
  __shared__ float tile[64][65];
  __shared__ float rn[64], sq[64];
  const int d0 = blockIdx.x * 64;   // 0..1023
  const int i0 = blockIdx.y * 64;   // 0..8191
  const int tr = threadIdx.x >> 6;  // 0..3
  const int tc = threadIdx.x & 63;
#pragma unroll
  for (int it = 0; it < 16; ++it) {
    int r = it * 4 + tr;
    tile[r][tc] = x[(size_t)(i0 + r) * 1024 + d0 + tc];
  }
  if (threadIdx.x < 64) {
    float rv = rnorm[i0 + threadIdx.x];
    rn[threadIdx.x] = rv;
    sq[threadIdx.x] = sqrtf(rv);
  }
  __syncthreads();
#pragma unroll
  for (int it = 0; it < 16; ++it) {
    int r = it * 4 + tr;
    Y[(size_t)(i0 + r) * 1024 + d0 + tc] = f2bf(tile[r][tc] * rn[r]);
  }
#pragma unroll
  for (int it = 0; it < 16; ++it) {
    int rr = it * 4 + tr;            // d within tile
    Wt[(size_t)(d0 + rr) * 8192 + i0 + tc] = f2bf(tile[tc][rr] * sq[tc]);
  }
}

// ---------------- GEMM: C = A[M][K] * B[N][K]^T, bf16 in, f32 acc ----------------
// R8-verified structure: BM=BN=128, BK=64, 4 waves (2x2), wave 64x64 = 4x4
// frags, ring-2 LDS (64KB, 2 blocks/CU), XOR-swizzle (0 conflicts), counted
// clobber-free vmcnt(8), fine ds_read/MFMA interleave with counted lgkm.
// MODE 0 (SYRK, LOWER-TRI): Z = Wt*Wt^T on the 36 lower-triangle 128^2 tiles
//   only (Z symmetric; R4/R5-verified), split-K=16, xcd=b&7 owns 2 K-slices
//   (2MB Wt band L2-resident). bf16 partials -> part[zi][tl][128][128].
// MODE 1: out = sigmoid(Y*Ztb^T + Y[i][d]*zdiag[d]) — diag term from bf16 Y
//   (= x*rn), dropping the 32MB f32 x re-read. 8 m-tiles per XCD.
template <int MODE>
__global__ __launch_bounds__(256, 2) void k_gemm128(
    const u16* __restrict__ A, const u16* __restrict__ B, void* __restrict__ Cv,
    const u16* __restrict__ Yd, const float* __restrict__ zdiag) {
  __shared__ char lds[2][32768] __attribute__((aligned(16)));
  const int tid = threadIdx.x;
  const int wave = tid >> 6;      // 0..3
  const int lane = tid & 63;
  const int wm = wave >> 1, wn = wave & 1;

  int m0, n0, k_start, K, nt;
  int zi = 0, tl = 0;
  if (MODE == 0) {
    // 576 blocks: xcd = b&7 owns K-slices {2xcd, 2xcd+1}; 36 lower-tri tiles
    const int orig = blockIdx.x;
    const int xcd = orig & 7;
    const int local = orig >> 3;            // 0..71
    const int half = (local >= 36) ? 1 : 0;
    tl = local - half * 36;                 // 0..35
    zi = xcd * 2 + half;                    // 0..15
    int tm = 0, a2 = 0;
    while (a2 + tm + 1 <= tl) { ++tm; a2 += tm; }
    const int tn = tl - a2;                 // tn <= tm
    m0 = tm * 128; n0 = tn * 128;
    k_start = zi * 512; K = 8192; nt = 8;
  } else {
    // 512 blocks: xcd = b&7 owns 8 m-tiles (2MB Y band + 2MB Ztb in L2)
    const int b = blockIdx.x;
    const int r = b >> 3;                   // 0..63
    m0 = (((b & 7) << 3) | (r >> 3)) * 128; // 64 m-tiles
    n0 = (r & 7) * 128;
    k_start = 0; K = 1024; nt = 16;
  }

  f32x4 acc[4][4] = {};

  const int frow = lane & 15;
  const u32 sw0 = (u32)(((lane >> 4) ^ (frow & 7)) << 4);  // swizzled 16B slot

  // staging: rows wave*32 + j*8 + (lane>>3), j=0..3; inverse-swizzled k-chunk
  const int srA = lane >> 3;
  const int swz8 = ((lane & 7) ^ srA) << 3;
  const u16* gA_l = A + (size_t)(m0 + wave * 32 + srA) * K + k_start + swz8;
  const u16* gB_l = B + (size_t)(n0 + wave * 32 + srA) * K + k_start + swz8;

  typedef __attribute__((address_space(3))) char* ldsp;
  ldsp l3 = (ldsp)((__attribute__((address_space(3))) void*)&lds[0][0]);
  const u32 lds0 = (u32)(uintptr_t)l3;

#define STAGE8(buf, kt)                                                        \
  do {                                                                         \
    const size_t _ko = (size_t)(kt) * 64;                                      \
    ldsp _ba = l3 + (buf) * 32768 + wave * 4096;                               \
    ldsp _bb = l3 + (buf) * 32768 + 16384 + wave * 4096;                       \
    _Pragma("unroll")                                                          \
    for (int _j = 0; _j < 4; ++_j)                                             \
      __builtin_amdgcn_global_load_lds(AS1(gA_l + _ko + (size_t)_j * 8 * K),   \
                                       (_ba + _j * 1024), 16, 0, 0);           \
    _Pragma("unroll")                                                          \
    for (int _j = 0; _j < 4; ++_j)                                             \
      __builtin_amdgcn_global_load_lds(AS1(gB_l + _ko + (size_t)_j * 8 * K),   \
                                       (_bb + _j * 1024), 16, 0, 0);           \
  } while (0)

#define MFMA4(ar, barr)                                                        \
  do {                                                                         \
    __builtin_amdgcn_s_setprio(1);                                             \
    acc[_mi][0] = __builtin_amdgcn_mfma_f32_16x16x32_bf16((ar), (barr)[0], acc[_mi][0], 0, 0, 0); \
    acc[_mi][1] = __builtin_amdgcn_mfma_f32_16x16x32_bf16((ar), (barr)[1], acc[_mi][1], 0, 0, 0); \
    acc[_mi][2] = __builtin_amdgcn_mfma_f32_16x16x32_bf16((ar), (barr)[2], acc[_mi][2], 0, 0, 0); \
    acc[_mi][3] = __builtin_amdgcn_mfma_f32_16x16x32_bf16((ar), (barr)[3], acc[_mi][3], 0, 0, 0); \
    __builtin_amdgcn_s_setprio(0);                                             \
  } while (0)

  STAGE8(0, 0);
  STAGE8(1, 1);
  for (int t = 0; t < nt; ++t) {
    const int buf = t & 1;
    if (t < nt - 1) { WAITV(8); } else { WAITV(0); }   // tile t landed; t+1 in flight
    __builtin_amdgcn_s_barrier();
    const u32 bb = lds0 + (u32)buf * 32768;
    const u32 aA = bb + (u32)((wm * 64 + frow) * 128) + sw0;
    const u32 aB = bb + 16384u + (u32)((wn * 64 + frow) * 128) + sw0;
    v8bf a0[4], a1[4], b0[4], b1[4];
    // issue order for counted lgkm (pure-DS, in-order): b0*4, a0[0], b1*4, a1[0]
    b0[0] = ds_read_b128f(aB);
    b0[1] = ds_read_b128f(aB + 2048);
    b0[2] = ds_read_b128f(aB + 4096);
    b0[3] = ds_read_b128f(aB + 6144);
    a0[0] = ds_read_b128f(aA);
    b1[0] = ds_read_b128f(aB ^ 0x40);
    b1[1] = ds_read_b128f((aB + 2048) ^ 0x40);
    b1[2] = ds_read_b128f((aB + 4096) ^ 0x40);
    b1[3] = ds_read_b128f((aB + 6144) ^ 0x40);
    a1[0] = ds_read_b128f(aA ^ 0x40);
    WAITL(5);                                   // b0*, a0[0] ready
    { const int _mi = 0; MFMA4(a0[0], b0); }
    a0[1] = ds_read_b128f(aA + 2048);
    a1[1] = ds_read_b128f((aA + 2048) ^ 0x40);
    WAITL(2);                                   // b1*, a1[0] ready
    { const int _mi = 0; MFMA4(a1[0], b1); }
    a0[2] = ds_read_b128f(aA + 4096);
    a1[2] = ds_read_b128f((aA + 4096) ^ 0x40);
    WAITL(3);                                   // a0[1] ready
    { const int _mi = 1; MFMA4(a0[1], b0); }
    a0[3] = ds_read_b128f(aA + 6144);
    a1[3] = ds_read_b128f((aA + 6144) ^ 0x40);
    WAITL(4);                                   // a1[1] ready
    { const int _mi = 1; MFMA4(a1[1], b1); }
    WAITL(3);                                   // a0[2] ready
    { const int _mi = 2; MFMA4(a0[2], b0); }
    WAITL(2);                                   // a1[2] ready
    { const int _mi = 2; MFMA4(a1[2], b1); }
    WAITL(1);                                   // a0[3] ready
    { const int _mi = 3; MFMA4(a0[3], b0); }
    WAITL(0);                                   // a1[3] ready
    { const int _mi = 3; MFMA4(a1[3], b1); }
    __builtin_amdgcn_s_barrier();               // all waves done with buf
    if (t + 2 < nt) STAGE8(buf, t + 2);         // in flight across tile t+1
  }
#undef STAGE8
#undef MFMA4

  // C/D layout (verified): col = lane&15, row = (lane>>4)*4 + reg
  const int crow = (lane >> 4) * 4;
  const int ccol = lane & 15;
#pragma unroll
  for (int mi = 0; mi < 4; ++mi) {
#pragma unroll
    for (int ni = 0; ni < 4; ++ni) {
      const int rl = wm * 64 + mi * 16 + crow;   // 0..127
      const int cl = wn * 64 + ni * 16 + ccol;   // 0..127
#pragma unroll
      for (int r = 0; r < 4; ++r) {
        float v = acc[mi][ni][r];
        if (MODE == 0) {
          // part[zi][tl][rl+r][cl] bf16
          const size_t o = (((size_t)(zi * 36 + tl)) << 14) + (size_t)(rl + r) * 128 + cl;
          ((u16*)Cv)[o] = f2bf(v);
        } else {
          const int row = m0 + rl + r;
          const int col = n0 + cl;
          const size_t o = (size_t)row * 1024 + col;
          // diag term: x[i][d]*rn[i]*zdiag[d] = Y[i][d]*zdiag[d] (Y bf16 exact-enough)
          float z = v + bf2f(Yd[o]) * zdiag[col];
          ((float*)Cv)[o] = 1.0f / (1.0f + __expf(-z));
        }
      }
    }
  }
}

// ---------------- K4: reduce 16 bf16 partials over lower-tri tiles -> full Ztb ----------------
// (R5-verified.) Each block: one 16-row slab of one lower tile. Sums 16
// partials -> Ztb[m][n]; off-diag tiles also write mirrored Ztb[n][m] via LDS
// transpose (Z symmetric). Diag elements -> zdiag (f32), zeroed in Ztb.
__global__ __launch_bounds__(256) void k_reduce2(const u16* __restrict__ part,
                                                 u16* __restrict__ Ztb,
                                                 float* __restrict__ zdiag) {
  __shared__ u16 t16[16][128];
  const int tile = blockIdx.x >> 3;
  const int slab = blockIdx.x & 7;
  int tm = 0, a2 = 0;
  while (a2 + tm + 1 <= tile) { ++tm; a2 += tm; }
  const int tn = tile - a2;

  const int rl = slab * 16 + (threadIdx.x >> 4);   // 0..127 row in tile
  const int cl0 = (threadIdx.x & 15) * 8;          // col start
  const size_t eo = (size_t)tile * 16384 + (size_t)rl * 128 + cl0;

  float s[8] = {0, 0, 0, 0, 0, 0, 0, 0};
#pragma unroll
  for (int p = 0; p < 16; ++p) {
    ushort8 pk = *(const ushort8*)(part + (size_t)p * (36 * 16384) + eo);
#pragma unroll
    for (int j = 0; j < 8; ++j) s[j] += bf2f(pk[j]);
  }
  const int m = tm * 128 + rl;
  ushort8 o;
#pragma unroll
  for (int j = 0; j < 8; ++j) {
    const int n = tn * 128 + cl0 + j;
    if (m == n) { zdiag[m] = s[j]; o[j] = 0; }
    else o[j] = f2bf(s[j]);
  }
  *(ushort8*)(Ztb + (size_t)m * 1024 + tn * 128 + cl0) = o;

  if (tm != tn) {
    *(ushort8*)(&t16[threadIdx.x >> 4][cl0]) = o;
    __syncthreads();
    // mirror: Ztb[tn*128 + c][tm*128 + slab*16 + k] = t16[k][c]
    const int c = threadIdx.x >> 1;
    const int kh = (threadIdx.x & 1) * 8;
    ushort8 g;
#pragma unroll
    for (int j = 0; j < 8; ++j) g[j] = t16[kh + j][c];
    *(ushort8*)(Ztb + (size_t)(tn * 128 + c) * 1024 + tm * 128 + slab * 16 + kh) = g;
  }
}

extern "C" void kernel_launch(void* const* d_in, const int* in_sizes, int n_in,
                              void* d_out, int out_size, void* d_ws, size_t ws_size,
                              hipStream_t stream) {
  const float* x = (const float*)d_in[0];
  float* out = (float*)d_out;
  char* ws = (char*)d_ws;

  // ws layout (~34.1 MB): rnorm | Y | Wt | Ztb | zdiag
  float* rnorm = (float*)ws;                                   // 32 KB
  u16* Y    = (u16*)(ws + (1u << 16));                         // 16 MB
  u16* Wt   = (u16*)(ws + (1u << 16) + (16u << 20));           // 16 MB
  u16* Ztb  = (u16*)(ws + (1u << 16) + (32u << 20));           // 2 MB
  float* zdiag = (float*)(ws + (1u << 16) + (34u << 20));      // 4 KB
  u16* part = (u16*)d_out;  // 16 slices x 36-tile bf16 partials (18.9 MB of 32 MB)

  k_rownorm<<<8192, 256, 0, stream>>>(x, rnorm);
  k_build<<<dim3(16, 128), 256, 0, stream>>>(x, rnorm, Y, Wt);
  // Z lower-tri: 36 tiles (128^2) x 16 K-slices = 576 blocks
  k_gemm128<0><<<576, 256, 0, stream>>>(Wt, Wt, part, nullptr, nullptr);
  k_reduce2<<<288, 256, 0, stream>>>(part, Ztb, zdiag);
  // out[i][d] = sigmoid( sum_k Y[i][k]*Ztb[d][k] + Y[i][d]*zdiag[d] ): 512 blocks
  k_gemm128<1><<<512, 256, 0, stream>>>(Y, Ztb, out, Y, zdiag);
}